// Round 4
// baseline (110.014 us; speedup 1.0000x reference)
//
#include <hip/hip_runtime.h>

// Problem constants (match reference)
#define NB 32768   // batch rows
#define NF 256     // features
#define NH 8       // hidden dim
#define ROWS_PER_BLOCK 32
#define NTHREADS 512

// Two threads per feature: each thread of a pair owns 4 of the 8 W2 columns,
// halving per-thread params (56 floats) so everything + a 32-row x prefetch
// fits in <=128 VGPR -> 4 waves/SIMD (launch_bounds(512,4)). h1 (8 fma+relu)
// is duplicated in the pair (cheap); the pair's partial dots merge with one
// __shfl_xor. Even lane stores w, odd lane stashes the row value in LDS;
// one barrier, then each wave reduces 4 rows and writes out_sum. No atomics.
__global__ __launch_bounds__(NTHREADS, 4) void NAM_49314814493074_kernel(
    const float* __restrict__ input,   // [B, F]
    const float* __restrict__ W1,      // [F, 8]
    const float* __restrict__ b1,      // [F, 8]
    const float* __restrict__ W2,      // [F, 8, 8]
    const float* __restrict__ b2,      // [F, 8]
    const float* __restrict__ W3,      // [F, 8]
    float* __restrict__ out_sum,       // [B]
    float* __restrict__ out_w)         // [B, F]
{
    __shared__ float sred[ROWS_PER_BLOCK][NF];   // 32 KB

    const int t    = threadIdx.x;
    const int f    = t >> 1;           // feature 0..255
    const int half = t & 1;            // which 4 columns of W2/b2/W3
    const int row0 = blockIdx.x * ROWS_PER_BLOCK;

    const float* xin = input + (size_t)row0 * NF + f;
    float* wout = out_w + (size_t)row0 * NF + f;

    // ---- prefetch all 32 x values into registers (loads all in flight) ----
    float xv[ROWS_PER_BLOCK];
    #pragma unroll
    for (int r = 0; r < ROWS_PER_BLOCK; ++r)
        xv[r] = xin[(size_t)r * NF];

    // ---- per-feature params (this thread's half) ----
    float w1[NH], bb1[NH];             // full, duplicated across the pair
    float w2[NH][4], bb2[4], w3[4];    // this thread's 4 columns
    {
        const float4* p1  = reinterpret_cast<const float4*>(W1 + (size_t)f * NH);
        const float4* pb1 = reinterpret_cast<const float4*>(b1 + (size_t)f * NH);
        float4 a, b;
        a = p1[0]; b = p1[1];
        w1[0]=a.x; w1[1]=a.y; w1[2]=a.z; w1[3]=a.w; w1[4]=b.x; w1[5]=b.y; w1[6]=b.z; w1[7]=b.w;
        a = pb1[0]; b = pb1[1];
        bb1[0]=a.x; bb1[1]=a.y; bb1[2]=a.z; bb1[3]=a.w; bb1[4]=b.x; bb1[5]=b.y; bb1[6]=b.z; bb1[7]=b.w;

        float4 c = reinterpret_cast<const float4*>(b2 + (size_t)f * NH)[half];
        bb2[0]=c.x; bb2[1]=c.y; bb2[2]=c.z; bb2[3]=c.w;
        c = reinterpret_cast<const float4*>(W3 + (size_t)f * NH)[half];
        w3[0]=c.x; w3[1]=c.y; w3[2]=c.z; w3[3]=c.w;

        const float4* p2 = reinterpret_cast<const float4*>(W2 + (size_t)f * NH * NH);
        #pragma unroll
        for (int h = 0; h < NH; ++h) {
            float4 d = p2[h * 2 + half];   // W2[f][h][half*4 .. half*4+3]
            w2[h][0]=d.x; w2[h][1]=d.y; w2[h][2]=d.z; w2[h][3]=d.w;
        }
    }

    // ---- compute all rows, fully unrolled ----
    #pragma unroll
    for (int r = 0; r < ROWS_PER_BLOCK; ++r) {
        const float x = xv[r];

        // h1 = relu(x * W1 + b1)  (duplicated in the pair)
        float h1[NH];
        #pragma unroll
        for (int h = 0; h < NH; ++h)
            h1[h] = fmaxf(fmaf(x, w1[h], bb1[h]), 0.0f);

        // this thread's 4 columns of h2 = relu(h1 @ W2 + b2)
        float acc[4];
        #pragma unroll
        for (int k = 0; k < 4; ++k) acc[k] = bb2[k];
        #pragma unroll
        for (int h = 0; h < NH; ++h) {
            #pragma unroll
            for (int k = 0; k < 4; ++k)
                acc[k] = fmaf(h1[h], w2[h][k], acc[k]);
        }

        // partial dot, then merge the pair (lanes 2f, 2f+1 are adjacent)
        float s = 0.0f;
        #pragma unroll
        for (int k = 0; k < 4; ++k)
            s = fmaf(fmaxf(acc[k], 0.0f), w3[k], s);
        s += __shfl_xor(s, 1, 64);

        if (half == 0)
            wout[(size_t)r * NF] = s;
        else
            sred[r][f] = s;
    }

    __syncthreads();

    // ---- per-row sums: 8 waves x 4 rows ----
    const int wave = t >> 6;
    const int lane = t & 63;
    #pragma unroll
    for (int rr = 0; rr < ROWS_PER_BLOCK / 8; ++rr) {
        const int r = wave * (ROWS_PER_BLOCK / 8) + rr;
        const float4 q = reinterpret_cast<const float4*>(&sred[r][0])[lane];
        float v = q.x + q.y + q.z + q.w;
        #pragma unroll
        for (int off = 32; off > 0; off >>= 1)
            v += __shfl_xor(v, off, 64);
        if (lane == 0)
            out_sum[row0 + r] = v;
    }
}

extern "C" void kernel_launch(void* const* d_in, const int* in_sizes, int n_in,
                              void* d_out, int out_size, void* d_ws, size_t ws_size,
                              hipStream_t stream) {
    const float* input = (const float*)d_in[0];
    const float* W1    = (const float*)d_in[1];
    const float* b1    = (const float*)d_in[2];
    const float* W2    = (const float*)d_in[3];
    const float* b2    = (const float*)d_in[4];
    const float* W3    = (const float*)d_in[5];

    float* out = (float*)d_out;          // [B] sums, then [B,F] w
    float* out_sum = out;
    float* out_w   = out + NB;

    dim3 grid(NB / ROWS_PER_BLOCK);      // 1024 blocks
    dim3 block(NTHREADS);                // 512 threads = 2 per feature
    NAM_49314814493074_kernel<<<grid, block, 0, stream>>>(
        input, W1, b1, W2, b2, W3, out_sum, out_w);
}

// Round 5
// 108.051 us; speedup vs baseline: 1.0182x; 1.0182x over previous
//
#include <hip/hip_runtime.h>

// Problem constants (match reference)
#define NB 32768   // batch rows
#define NF 256     // features
#define NH 8       // hidden dim
#define ROWS_PER_BLOCK 32
#define CH 8       // prefetch chunk (rows)

// One thread per feature; 96 MLP params in registers. Param loads are issued
// FIRST (the only exposed latency), then row inputs are prefetched in
// software-pipelined chunks of 8 (xA/xB double buffer) so every x-load
// overlaps the previous chunk's ~800-instruction compute stream.
// launch_bounds(256,3): VGPR cap ~170 (no spill for ~135 live), 3 waves/SIMD.
// Row sums via one barrier + per-wave LDS reads + shuffle butterfly.
__global__ __launch_bounds__(256, 3) void NAM_49314814493074_kernel(
    const float* __restrict__ input,   // [B, F]
    const float* __restrict__ W1,      // [F, 8]
    const float* __restrict__ b1,      // [F, 8]
    const float* __restrict__ W2,      // [F, 8, 8]
    const float* __restrict__ b2,      // [F, 8]
    const float* __restrict__ W3,      // [F, 8]
    float* __restrict__ out_sum,       // [B]
    float* __restrict__ out_w)         // [B, F]
{
    __shared__ float sred[ROWS_PER_BLOCK][NF];   // 32 KB

    const int f = threadIdx.x;                  // feature index 0..255
    const int row0 = blockIdx.x * ROWS_PER_BLOCK;

    // ---- params first: the only loads whose latency is ever exposed ----
    float w1[NH], bb1[NH], bb2[NH], w3[NH];
    float w2[NH][NH];
    {
        const float4* p1  = reinterpret_cast<const float4*>(W1 + (size_t)f * NH);
        const float4* pb1 = reinterpret_cast<const float4*>(b1 + (size_t)f * NH);
        const float4* pb2 = reinterpret_cast<const float4*>(b2 + (size_t)f * NH);
        const float4* p3  = reinterpret_cast<const float4*>(W3 + (size_t)f * NH);
        float4 a, b;
        a = p1[0]; b = p1[1];
        w1[0]=a.x; w1[1]=a.y; w1[2]=a.z; w1[3]=a.w; w1[4]=b.x; w1[5]=b.y; w1[6]=b.z; w1[7]=b.w;
        a = pb1[0]; b = pb1[1];
        bb1[0]=a.x; bb1[1]=a.y; bb1[2]=a.z; bb1[3]=a.w; bb1[4]=b.x; bb1[5]=b.y; bb1[6]=b.z; bb1[7]=b.w;
        a = pb2[0]; b = pb2[1];
        bb2[0]=a.x; bb2[1]=a.y; bb2[2]=a.z; bb2[3]=a.w; bb2[4]=b.x; bb2[5]=b.y; bb2[6]=b.z; bb2[7]=b.w;
        a = p3[0]; b = p3[1];
        w3[0]=a.x; w3[1]=a.y; w3[2]=a.z; w3[3]=a.w; w3[4]=b.x; w3[5]=b.y; w3[6]=b.z; w3[7]=b.w;

        const float4* p2 = reinterpret_cast<const float4*>(W2 + (size_t)f * NH * NH);
        #pragma unroll
        for (int h = 0; h < NH; ++h) {
            float4 c0 = p2[h * 2 + 0];
            float4 c1 = p2[h * 2 + 1];
            w2[h][0]=c0.x; w2[h][1]=c0.y; w2[h][2]=c0.z; w2[h][3]=c0.w;
            w2[h][4]=c1.x; w2[h][5]=c1.y; w2[h][6]=c1.z; w2[h][7]=c1.w;
        }
    }

    const float* xin = input + (size_t)row0 * NF + f;
    float* wout = out_w + (size_t)row0 * NF + f;

    float xA[CH], xB[CH];

    // per-row MLP: ~96 VALU ops, ends with coalesced store + LDS stash.
    // r0 may be runtime-propagated; only xb's index must be static (unrolled i).
    auto compute8 = [&](float (&xb)[CH], int r0) {
        #pragma unroll
        for (int i = 0; i < CH; ++i) {
            const float x = xb[i];
            float h1[NH];
            #pragma unroll
            for (int h = 0; h < NH; ++h)
                h1[h] = fmaxf(fmaf(x, w1[h], bb1[h]), 0.0f);

            float acc[NH];
            #pragma unroll
            for (int k = 0; k < NH; ++k)       // fold init into h=0 FMA
                acc[k] = fmaf(h1[0], w2[0][k], bb2[k]);
            #pragma unroll
            for (int h = 1; h < NH; ++h) {
                #pragma unroll
                for (int k = 0; k < NH; ++k)
                    acc[k] = fmaf(h1[h], w2[h][k], acc[k]);
            }

            float s = 0.0f;
            #pragma unroll
            for (int k = 0; k < NH; ++k)
                s = fmaf(fmaxf(acc[k], 0.0f), w3[k], s);

            const int r = r0 + i;
            wout[(size_t)r * NF] = s;
            sred[r][f] = s;
        }
    };

    // ---- software pipeline: load chunk c+1 while computing chunk c ----
    #pragma unroll
    for (int i = 0; i < CH; ++i) xA[i] = xin[(size_t)i * NF];

    #pragma unroll
    for (int i = 0; i < CH; ++i) xB[i] = xin[(size_t)(CH + i) * NF];
    compute8(xA, 0);

    #pragma unroll
    for (int i = 0; i < CH; ++i) xA[i] = xin[(size_t)(2 * CH + i) * NF];
    compute8(xB, CH);

    #pragma unroll
    for (int i = 0; i < CH; ++i) xB[i] = xin[(size_t)(3 * CH + i) * NF];
    compute8(xA, 2 * CH);

    compute8(xB, 3 * CH);

    __syncthreads();

    // ---- per-row sums: 4 waves x 8 rows ----
    const int wave = threadIdx.x >> 6;
    const int lane = threadIdx.x & 63;
    #pragma unroll
    for (int rr = 0; rr < ROWS_PER_BLOCK / 4; ++rr) {
        const int r = wave * (ROWS_PER_BLOCK / 4) + rr;
        const float4 q = reinterpret_cast<const float4*>(&sred[r][0])[lane];
        float v = q.x + q.y + q.z + q.w;
        #pragma unroll
        for (int off = 32; off > 0; off >>= 1)
            v += __shfl_xor(v, off, 64);
        if (lane == 0)
            out_sum[row0 + r] = v;
    }
}

extern "C" void kernel_launch(void* const* d_in, const int* in_sizes, int n_in,
                              void* d_out, int out_size, void* d_ws, size_t ws_size,
                              hipStream_t stream) {
    const float* input = (const float*)d_in[0];
    const float* W1    = (const float*)d_in[1];
    const float* b1    = (const float*)d_in[2];
    const float* W2    = (const float*)d_in[3];
    const float* b2    = (const float*)d_in[4];
    const float* W3    = (const float*)d_in[5];

    float* out = (float*)d_out;          // [B] sums, then [B,F] w
    float* out_sum = out;
    float* out_w   = out + NB;

    dim3 grid(NB / ROWS_PER_BLOCK);      // 1024 blocks
    dim3 block(NF);                      // 256 threads = 1 per feature
    NAM_49314814493074_kernel<<<grid, block, 0, stream>>>(
        input, W1, b1, W2, b2, W3, out_sum, out_w);
}